// Round 11
// baseline (864.297 us; speedup 1.0000x reference)
//
#include <hip/hip_runtime.h>
#include <hip/hip_fp16.h>
#include <math.h>

#define D 32
#define SLOPE 0.2f
#define GAT_EPS 1e-16f
#define NBLK 512        // chunk-blocks in hist/scat passes

// Coarse bucket = 256 nodes (dst>>8), NB = ceil(N/256) <= 256 (requires N <= 65536;
// here N=50000). Edge payload packed as (local_dst<<16)|src (src < 65536).

// K1 (fused): blocks [0,NBLK) -> per-chunk LDS histogram of dst buckets;
//             blocks [NBLK, NBLK+gLin) -> layer-1 linear (independent work).
__global__ void k_hist_lin(const int* __restrict__ dst, int* __restrict__ cnt,
                           const float* __restrict__ x, const float* __restrict__ W,
                           const float* __restrict__ a_src, const float* __restrict__ a_dst,
                           __half* __restrict__ h16, float* __restrict__ ssrc,
                           float* __restrict__ sdst,
                           int N, int E, int Etot, int NB) {
    __shared__ int hist[256];
    __shared__ float Ws[D * D];
    __shared__ float xs[8 * D];
    int tid = threadIdx.x;
    if (blockIdx.x < NBLK) {
        int blk = blockIdx.x;
        hist[tid] = 0;
        __syncthreads();
        int chunk = (Etot + NBLK - 1) / NBLK;
        int lo = blk * chunk, hi = min(Etot, lo + chunk);
        for (int i = lo + tid; i < hi; i += 256) {
            int t = (i < E) ? dst[i] : i - E;
            atomicAdd(&hist[t >> 8], 1);
        }
        __syncthreads();
        if (tid < NB) cnt[tid * NBLK + blk] = hist[tid];
    } else {
        for (int i = tid; i < D * D; i += 256) Ws[i] = W[i];
        int base = (blockIdx.x - NBLK) * 8;
        int gidx = base * D + tid;
        xs[tid] = (gidx < N * D) ? x[gidx] : 0.0f;
        __syncthreads();
        int r = tid >> 5, d = tid & 31;
        int n = base + r;
        if (n >= N) return;
        float acc = 0.0f;
#pragma unroll
        for (int k = 0; k < D; ++k) acc += xs[r * D + k] * Ws[k * D + d];
        h16[n * D + d] = __float2half(acc);
        float vs = acc * a_src[d];
        float vd = acc * a_dst[d];
#pragma unroll
        for (int off = 16; off > 0; off >>= 1) {
            vs += __shfl_xor(vs, off, 32);
            vd += __shfl_xor(vd, off, 32);
        }
        if (d == 0) { ssrc[n] = vs; sdst[n] = vd; }
    }
}

// K2: one block per bucket: exclusive scan of its NBLK chunk-counts (in place);
// bucket total -> btot[b].
__global__ void k_scans(int* __restrict__ cnt, int* __restrict__ btot, int NB) {
    __shared__ int arr[256];
    int t = threadIdx.x, b = blockIdx.x;
    int base = b * NBLK + 2 * t;
    int c0 = cnt[base], c1 = cnt[base + 1];
    int ps = c0 + c1;
    arr[t] = ps;
    __syncthreads();
    for (int off = 1; off < 256; off <<= 1) {
        int u = (t >= off) ? arr[t - off] : 0;
        __syncthreads();
        arr[t] += u;
        __syncthreads();
    }
    int excl = arr[t] - ps;
    cnt[base] = excl;
    cnt[base + 1] = excl + c0;
    if (t == 255) btot[b] = arr[255];
}

// K3: re-read chunk, scatter packed (dl<<16)|src via LDS cursors.
// Each block locally scans btot (NB<=256 values) to get bucket bases.
__global__ void k_scat(const int* __restrict__ src, const int* __restrict__ dst,
                       const int* __restrict__ cnt, const int* __restrict__ btot,
                       unsigned int* __restrict__ bufP, int E, int Etot, int NB) {
    __shared__ int arr[256];
    __shared__ int lcur[256];
    int t = threadIdx.x, blk = blockIdx.x;
    int v0 = (t < NB) ? btot[t] : 0;
    arr[t] = v0;
    __syncthreads();
    for (int off = 1; off < 256; off <<= 1) {
        int u = (t >= off) ? arr[t - off] : 0;
        __syncthreads();
        arr[t] += u;
        __syncthreads();
    }
    if (t < NB) lcur[t] = (arr[t] - v0) + cnt[t * NBLK + blk];
    __syncthreads();
    int chunk = (Etot + NBLK - 1) / NBLK;
    int lo = blk * chunk, hi = min(Etot, lo + chunk);
    for (int i = lo + t; i < hi; i += 256) {
        int s, tg;
        if (i < E) { s = src[i]; tg = dst[i]; } else { s = tg = i - E; }
        int p = atomicAdd(&lcur[tg >> 8], 1);
        bufP[p] = ((unsigned int)(tg & 255) << 16) | (unsigned int)s;
    }
}

// K4: bucket-level fused softmax + aggregation. One block per bucket, one THREAD
// per edge. LDS acc[d][dl] (bank = dl%32 -> random dl gives ~2 lanes/bank, free)
// + den[dl]. Max-free softmax (logits bounded; e/sum(e) shift-invariant).
// Epilogue: normalize + bias + ELU, coalesced store.
__global__ __launch_bounds__(1024)
void k_bagg(const unsigned int* __restrict__ bufP, const int* __restrict__ btot,
            const float* __restrict__ ssrc, const float* __restrict__ sdst,
            const __half* __restrict__ h16, const float* __restrict__ bias,
            float* __restrict__ out, int N, int NB) {
    __shared__ float accS[D * 256];   // [d][dl], 32 KB
    __shared__ float denS[256];
    __shared__ float sdS[256];
    __shared__ int   arr[256];
    __shared__ float biasS[D];
    int b = blockIdx.x, t = threadIdx.x;

    if (t < 256) arr[t] = (t < NB) ? btot[t] : 0;
    if (t >= 256 && t < 256 + D) biasS[t - 256] = bias[t - 256];
    __syncthreads();
    for (int off = 1; off < 256; off <<= 1) {
        int u = 0;
        if (t < 256 && t >= off) u = arr[t - off];
        __syncthreads();
        if (t < 256) arr[t] += u;
        __syncthreads();
    }
    int hi = arr[b];
    int lo = hi - btot[b];

    for (int i = t; i < D * 256; i += 1024) accS[i] = 0.0f;
    if (t < 256) {
        denS[t] = 0.0f;
        int n = (b << 8) + t;
        sdS[t] = (n < N) ? sdst[n] : 0.0f;
    }
    __syncthreads();

    for (int i = lo + t; i < hi; i += 1024) {
        unsigned int v = bufP[i];
        int dl = (int)(v >> 16);
        int s  = (int)(v & 0xFFFFu);
        float l = ssrc[s] + sdS[dl];
        float e = __expf(fmaxf(l, SLOPE * l));
        atomicAdd(&denS[dl], e);
        const float4* hp4 = (const float4*)(h16 + (size_t)s * D);
        float4 q0 = hp4[0], q1 = hp4[1], q2 = hp4[2], q3 = hp4[3];
        float4 qs[4] = {q0, q1, q2, q3};
        const __half2* hh = (const __half2*)qs;
#pragma unroll
        for (int j = 0; j < 16; ++j) {
            float2 f = __half22float2(hh[j]);
            atomicAdd(&accS[(2 * j) * 256 + dl],     e * f.x);
            atomicAdd(&accS[(2 * j + 1) * 256 + dl], e * f.y);
        }
    }
    __syncthreads();

    int nbase = b << 8;
    for (int idx = t; idx < 256 * D; idx += 1024) {
        int dl = idx >> 5, d = idx & 31;
        int n = nbase + dl;
        if (n < N) {
            float vo = accS[d * 256 + dl] / (denS[dl] + GAT_EPS) + biasS[d];
            out[(size_t)n * D + d] = (vo > 0.0f) ? vo : expm1f(vo);
        }
    }
}

// standalone linear (layer 2): h16 = fp16(x @ W); fused per-node scores.
__global__ void k_linear(const float* __restrict__ x, const float* __restrict__ W,
                         const float* __restrict__ a_src, const float* __restrict__ a_dst,
                         __half* __restrict__ h16, float* __restrict__ ssrc,
                         float* __restrict__ sdst, int N) {
    __shared__ float Ws[D * D];
    __shared__ float xs[8 * D];
    int tid = threadIdx.x;
    for (int i = tid; i < D * D; i += 256) Ws[i] = W[i];
    int base = blockIdx.x * 8;
    int gidx = base * D + tid;
    xs[tid] = (gidx < N * D) ? x[gidx] : 0.0f;
    __syncthreads();
    int r = tid >> 5, d = tid & 31;
    int n = base + r;
    if (n >= N) return;
    float acc = 0.0f;
#pragma unroll
    for (int k = 0; k < D; ++k) acc += xs[r * D + k] * Ws[k * D + d];
    h16[n * D + d] = __float2half(acc);
    float vs = acc * a_src[d];
    float vd = acc * a_dst[d];
#pragma unroll
    for (int off = 16; off > 0; off >>= 1) {
        vs += __shfl_xor(vs, off, 32);
        vd += __shfl_xor(vd, off, 32);
    }
    if (d == 0) { ssrc[n] = vs; sdst[n] = vd; }
}

extern "C" void kernel_launch(void* const* d_in, const int* in_sizes, int n_in,
                              void* d_out, int out_size, void* d_ws, size_t ws_size,
                              hipStream_t stream) {
    const float* x   = (const float*)d_in[0];
    const int*   ei  = (const int*)d_in[1];
    const float* W1  = (const float*)d_in[2];
    const float* as1 = (const float*)d_in[3];
    const float* ad1 = (const float*)d_in[4];
    const float* b1  = (const float*)d_in[5];
    const float* W2  = (const float*)d_in[6];
    const float* as2 = (const float*)d_in[7];
    const float* ad2 = (const float*)d_in[8];
    const float* b2  = (const float*)d_in[9];

    const int N = in_sizes[0] / D;
    const int E = in_sizes[1] / 2;
    const int Etot = E + N;
    const int NB = (N + 255) >> 8;      // 196 coarse buckets for N=50000

    float* out  = (float*)d_out;
    float* xbar = out;                    // first output chunk
    float* z    = out + (size_t)N * D;    // second output chunk (layer-2 input)

    unsigned int* bufP = (unsigned int*)d_ws;              // Etot
    __half*       h16  = (__half*)(bufP + Etot);           // N*D halves
    float*        ssrc = (float*)(h16 + (size_t)N * D);    // N
    float*        sdst = ssrc + N;                         // N
    int*          cnt  = (int*)(sdst + N);                 // NB*NBLK
    int*          btot = cnt + NB * NBLK;                  // NB

    const int* srcA = ei;
    const int* dstA = ei + E;

    const int gLin = (N + 7) / 8;

    // K1: histogram (chunk blocks) fused with layer-1 linear (independent)
    k_hist_lin<<<NBLK + gLin, 256, 0, stream>>>(dstA, cnt, x, W1, as1, ad1,
                                                h16, ssrc, sdst, N, E, Etot, NB);
    // K2..K3: finish bucket sort
    k_scans<<<NB, 256, 0, stream>>>(cnt, btot, NB);
    k_scat <<<NBLK, 256, 0, stream>>>(srcA, dstA, cnt, btot, bufP, E, Etot, NB);

    // layer 1: bucket aggregation -> z
    k_bagg<<<NB, 1024, 0, stream>>>(bufP, btot, ssrc, sdst, h16, b1, z, N, NB);

    // layer 2
    k_linear<<<gLin, 256, 0, stream>>>(z, W2, as2, ad2, h16, ssrc, sdst, N);
    k_bagg<<<NB, 1024, 0, stream>>>(bufP, btot, ssrc, sdst, h16, b2, xbar, N, NB);
}